// Round 16
// baseline (256.919 us; speedup 1.0000x reference)
//
#include <hip/hip_runtime.h>
#include <hip/hip_bf16.h>
#include <math.h>

// n=1, t=3(=L), c=64, h=w=64, M=8, D=8, P=12, KK=9
#define HWN 4096
// fp8 dual-copy value layout: [24 lm][36 yp][72 x][2 slot][8 ch] BYTES
#define VROW 72
#define VYP 36
#define VSZ_B (24 * VYP * VROW * 16)   // 995328 bytes per copy

typedef __attribute__((ext_vector_type(8))) short short8;
typedef __attribute__((ext_vector_type(4))) float f32x4;
typedef __attribute__((ext_vector_type(2))) float f32x2;

__device__ __forceinline__ float lrelu_f(float v) { return v >= 0.f ? v : 0.1f * v; }

__device__ __forceinline__ unsigned short f2bf(float f) {
  union { float f; unsigned u; } v; v.f = f;
  unsigned r = v.u + 0x7fff + ((v.u >> 16) & 1);   // round-to-nearest-even
  return (unsigned short)(r >> 16);
}
__device__ __forceinline__ float bf2f(unsigned short u) {
  union { unsigned u; float f; } v; v.u = ((unsigned)u) << 16; return v.f;
}
__device__ __forceinline__ float bf_lo(unsigned u) {
  union { unsigned u; float f; } v; v.u = u << 16; return v.f;
}
__device__ __forceinline__ float bf_hi(unsigned u) {
  union { unsigned u; float f; } v; v.u = u & 0xffff0000u; return v.f;
}
// word-select must be an immediate constant -> template parameter
template <bool HI>
__device__ __forceinline__ f32x2 cvt8(unsigned u) {
  return __builtin_amdgcn_cvt_pk_f32_fp8((int)u, HI);
}

__device__ __forceinline__ float bilin_zero(const float* __restrict__ img, float ix, float iy) {
  float fx0 = floorf(ix), fy0 = floorf(iy);
  int x0 = (int)fx0, y0 = (int)fy0;
  float wx1 = ix - fx0, wy1 = iy - fy0;
  float wx0 = 1.f - wx1, wy0 = 1.f - wy1;
  float acc = 0.f;
  if ((unsigned)y0 < 64u) {
    if ((unsigned)x0 < 64u)       acc += wx0 * wy0 * img[y0 * 64 + x0];
    if ((unsigned)(x0 + 1) < 64u) acc += wx1 * wy0 * img[y0 * 64 + x0 + 1];
  }
  if ((unsigned)(y0 + 1) < 64u) {
    if ((unsigned)x0 < 64u)       acc += wx0 * wy1 * img[(y0 + 1) * 64 + x0];
    if ((unsigned)(x0 + 1) < 64u) acc += wx1 * wy1 * img[(y0 + 1) * 64 + x0 + 1];
  }
  return acc;
}

// k_pre segments (by blockIdx.x):
// [0,864) Wtail | [864,912) biases+op | [912,1080) W1 | [1080,1464) W2g/W3g
// [1464,1608) vpb | [1608,1800) x transpose | [1800,1816) flow_cn2
// [1816,2302) zero v8 (fp8, 2*VSZ_B bytes)
__global__ void k_pre(
    const float* __restrict__ x, const float* __restrict__ flow1, const float* __restrict__ flow2,
    const float* so_w4, const float* po_w4, const float* aw_w4,
    const float* so_b4, const float* po_b4, const float* aw_b4,
    const float* so_b1, const float* po_b1, const float* aw_b1,
    const float* so_b2, const float* po_b2, const float* aw_b2,
    const float* so_b3, const float* po_b3, const float* aw_b3,
    const float* so_w1, const float* po_w1, const float* aw_w1,
    const float* so_w2, const float* po_w2, const float* aw_w2,
    const float* so_w3, const float* po_w3, const float* aw_w3,
    const float* op_w1, const float* op_w2, const float* vp_w,
    unsigned short* Wtail, float* btail, float* b1c, float* b2c, float* b3c,
    unsigned short* o1b, unsigned short* o2b, unsigned short* W1,
    unsigned short* W2g, unsigned short* W3g, unsigned short* vpb,
    unsigned short* xb, float* fcn2, unsigned char* v8) {
  __shared__ unsigned short tile[64 * 65];
  __shared__ unsigned short wrow[576];
  int gx = blockIdx.x;
  int tid = threadIdx.x;
  if (gx < 864) {  // Wtail [3456][64]
    int t = gx * 256 + tid;
    int row = t >> 6, k = t & 63;
    float v = row < 576 ? so_w4[row * 64 + k]
            : row < 864 ? po_w4[(row - 576) * 64 + k]
                        : aw_w4[(row - 864) * 64 + k];
    Wtail[t] = f2bf(v);
  } else if (gx < 912) {
    int t = (gx - 864) * 256 + tid;
    if (t < 3456) {
      btail[t] = t < 576 ? so_b4[t] : t < 864 ? po_b4[t - 576] : aw_b4[t - 864];
    } else if (t < 3648) {
      int i = t - 3456; b1c[i] = i < 64 ? so_b1[i] : i < 128 ? po_b1[i - 64] : aw_b1[i - 128];
    } else if (t < 3840) {
      int i = t - 3648; b2c[i] = i < 64 ? so_b2[i] : i < 128 ? po_b2[i - 64] : aw_b2[i - 128];
    } else if (t < 4032) {
      int i = t - 3840; b3c[i] = i < 64 ? so_b3[i] : i < 128 ? po_b3[i - 64] : aw_b3[i - 128];
    } else if (t < 8128) {
      o1b[t - 4032] = f2bf(op_w1[t - 4032]);
    } else if (t < 12224) {
      o2b[t - 8128] = f2bf(op_w2[t - 8128]);
    }
  } else if (gx < 1080) {  // W1 [192][224] zero-padded K
    int t = (gx - 912) * 256 + tid;
    if (t < 192 * 224) {
      int row = t / 224, k = t % 224;
      int tr = row >> 6, lco = row & 63;
      const float* s = tr == 0 ? so_w1 : tr == 1 ? po_w1 : aw_w1;
      W1[t] = (k < 196) ? f2bf(s[lco * 196 + k]) : (unsigned short)0;
    }
  } else if (gx < 1464) {  // W2g/W3g LDS transpose
    int b = gx - 1080;
    int which = b >= 192;
    b &= 191;
    int tr = b >> 6, co = b & 63;
    const float* s;
    if (!which) s = tr == 0 ? so_w2 : tr == 1 ? po_w2 : aw_w2;
    else        s = tr == 0 ? so_w3 : tr == 1 ? po_w3 : aw_w3;
    unsigned short* d = which ? W3g : W2g;
#pragma unroll
    for (int j = tid; j < 576; j += 256) wrow[j] = f2bf(s[co * 576 + j]);
    __syncthreads();
#pragma unroll
    for (int j = tid; j < 576; j += 256)
      d[((size_t)tr * 64 + co) * 576 + j] = wrow[(j & 63) * 9 + (j >> 6)];
  } else if (gx < 1608) {  // vpb [192][192]
    int t = (gx - 1464) * 256 + tid;
    if (t < 192 * 192) vpb[t] = f2bf(vp_w[t]);
  } else if (gx < 1800) {  // x transpose -> xb [p][192]
    int b = gx - 1608;
    int ptile = b & 63, cg = b >> 6;  // 64 x 3
    int px = tid & 63, ch0 = (tid >> 6) * 16;
#pragma unroll
    for (int i = 0; i < 16; i++) {
      float v = x[(size_t)(cg * 64 + ch0 + i) * HWN + ptile * 64 + px];
      tile[(ch0 + i) * 65 + px] = f2bf(v);
    }
    __syncthreads();
    int c = tid & 63, pl0 = (tid >> 6) * 16;
#pragma unroll
    for (int i = 0; i < 16; i++)
      xb[(size_t)(ptile * 64 + pl0 + i) * 192 + cg * 64 + c] = tile[c * 65 + pl0 + i];
  } else if (gx < 1816) {  // flow_cn2
    int p = (gx - 1800) * 256 + tid;
    int px = p & 63, py = p >> 6;
    float fx = flow1[p], fy = flow1[HWN + p];
    float ix = (float)px + fx, iy = (float)py + fy;
    fcn2[p] = fx + bilin_zero(flow2, ix, iy);
    fcn2[HWN + p] = fy + bilin_zero(flow2 + HWN, ix, iy);
  } else {  // zero fp8 tables: 2*VSZ_B/16 = 124416 uint4
    int i = (gx - 1816) * 256 + tid;
    if (i < 2 * VSZ_B / 16) ((uint4*)v8)[i] = make_uint4(0, 0, 0, 0);
  }
}

// k_extra: wave per pixel, lane = channel. All accesses coalesced.
__global__ void k_extra(const unsigned short* __restrict__ xb, const float* __restrict__ flow1,
                        const float* __restrict__ fcn2, unsigned short* __restrict__ extra) {
  int w = threadIdx.x >> 6, c = threadIdx.x & 63;
  int p = blockIdx.x * 4 + w;
  int px = p & 63, py = p >> 6;
  float fx1 = flow1[p], fy1 = flow1[HWN + p];
  float fx2 = fcn2[p],  fy2 = fcn2[HWN + p];
  extra[(size_t)p * 224 + c] = xb[(size_t)p * 192 + c];
#pragma unroll
  for (int lev = 0; lev < 2; lev++) {
    float ix = (float)px + (lev ? fx2 : fx1);
    float iy = (float)py + (lev ? fy2 : fy1);
    float fx0 = floorf(ix), fy0 = floorf(iy);
    int x0 = (int)fx0, y0 = (int)fy0;
    float wx1 = ix - fx0, wy1 = iy - fy0;
    float wx0 = 1.f - wx1, wy0 = 1.f - wy1;
    int coff = (lev + 1) * 64;
    float acc = 0.f;
    if ((unsigned)y0 < 64u) {
      if ((unsigned)x0 < 64u)       acc += wx0 * wy0 * bf2f(xb[(size_t)(y0 * 64 + x0) * 192 + coff + c]);
      if ((unsigned)(x0 + 1) < 64u) acc += wx1 * wy0 * bf2f(xb[(size_t)(y0 * 64 + x0 + 1) * 192 + coff + c]);
    }
    if ((unsigned)(y0 + 1) < 64u) {
      if ((unsigned)x0 < 64u)       acc += wx0 * wy1 * bf2f(xb[(size_t)((y0 + 1) * 64 + x0) * 192 + coff + c]);
      if ((unsigned)(x0 + 1) < 64u) acc += wx1 * wy1 * bf2f(xb[(size_t)((y0 + 1) * 64 + x0 + 1) * 192 + coff + c]);
    }
    extra[(size_t)p * 224 + coff + c] = f2bf(acc);
  }
  if (c < 2) {
    extra[(size_t)p * 224 + 192 + c] = f2bf(flow1[c * HWN + p]);
    extra[(size_t)p * 224 + 194 + c] = f2bf(fcn2[c * HWN + p]);
  }
  if (c < 28) extra[(size_t)p * 224 + 196 + c] = 0;
}

// Two GEMMs in one dispatch (blockIdx.z): z=0 value-proj (K=192), z=1 trunk head (K=224, lrelu).
__global__ __launch_bounds__(128) void k_gemm2(
    const unsigned short* __restrict__ A0, const unsigned short* __restrict__ Wm0,
    const float* __restrict__ bias0, unsigned short* __restrict__ out0,
    const unsigned short* __restrict__ A1, const unsigned short* __restrict__ Wm1,
    const float* __restrict__ bias1, unsigned short* __restrict__ out1) {
  int z = blockIdx.z;
  const unsigned short* A = z ? A1 : A0;
  const unsigned short* Wm = z ? Wm1 : Wm0;
  const float* bias = z ? bias1 : bias0;
  unsigned short* out = z ? out1 : out0;
  int K = z ? 224 : 192;

  int wv = threadIdx.x >> 6;
  int l = threadIdx.x & 63;
  int lm = l & 15, lq = l >> 4;
  int p0 = blockIdx.x * 32 + wv * 16;
  int co0 = blockIdx.y * 32;

  f32x4 acc[2];
#pragma unroll
  for (int nt = 0; nt < 2; nt++) {
    float bv = bias[co0 + nt * 16 + lm];
    acc[nt] = (f32x4){bv, bv, bv, bv};
  }
  const unsigned short* ap = A + (size_t)(p0 + lm) * K + lq * 8;
  const unsigned short* wp = Wm + (size_t)(co0 + lm) * K + lq * 8;
  for (int k0 = 0; k0 < K; k0 += 32) {
    short8 af = *(const short8*)(ap + k0);
#pragma unroll
    for (int nt = 0; nt < 2; nt++) {
      short8 bf = *(const short8*)(wp + (size_t)nt * 16 * K + k0);
      acc[nt] = __builtin_amdgcn_mfma_f32_16x16x32_bf16(af, bf, acc[nt], 0, 0, 0);
    }
  }
#pragma unroll
  for (int nt = 0; nt < 2; nt++) {
    int co = co0 + nt * 16 + lm;
#pragma unroll
    for (int r = 0; r < 4; r++) {
      int p = p0 + lq * 4 + r;
      float v = acc[nt][r];
      if (z) v = lrelu_f(v);
      out[(size_t)p * 192 + co] = f2bf(v);
    }
  }
}

// Grouped direct 3x3 conv (pad 1) h1->h2; z==3 plane: fp8 value repack.
__global__ __launch_bounds__(128) void k_conv3g(const unsigned short* __restrict__ h,
                                                const unsigned short* __restrict__ Wm,
                                                const float* __restrict__ bias,
                                                unsigned short* __restrict__ out,
                                                const unsigned short* __restrict__ vsb,
                                                unsigned char* __restrict__ v8) {
  if (blockIdx.z == 3) {  // repack vsb [p][192] bf16 -> fp8 dual copies
    int b = blockIdx.y * 128 + blockIdx.x;   // 0..511
    int i = b * 128 + threadIdx.x;           // 0..65535
#pragma unroll
    for (int rep = 0; rep < 2; rep++, i += 65536) {
      if (i < 98304) {
        int lm = i % 24, p = i / 24;
        uint4 vv = ((const uint4*)vsb)[p * 24 + lm];
        int lo = 0, hi = 0;
        lo = __builtin_amdgcn_cvt_pk_fp8_f32(bf_lo(vv.x), bf_hi(vv.x), lo, false);
        lo = __builtin_amdgcn_cvt_pk_fp8_f32(bf_lo(vv.y), bf_hi(vv.y), lo, true);
        hi = __builtin_amdgcn_cvt_pk_fp8_f32(bf_lo(vv.z), bf_hi(vv.z), hi, false);
        hi = __builtin_amdgcn_cvt_pk_fp8_f32(bf_lo(vv.w), bf_hi(vv.w), hi, true);
        uint2 pk; pk.x = (unsigned)lo; pk.y = (unsigned)hi;
        int y = p >> 6, xx = p & 63;
        int ypA = (y >> 1) + 1, slotA = y & 1;
        int ypB = (y + 1) >> 1, slotB = (y & 1) ^ 1;
        *(uint2*)(v8 + (((lm * VYP + ypA) * VROW + xx + 2) * 16 + slotA * 8)) = pk;
        *(uint2*)(v8 + VSZ_B + (((lm * VYP + ypB) * VROW + xx + 2) * 16 + slotB * 8)) = pk;
      }
    }
    return;
  }
  int wv = threadIdx.x >> 6;
  int l = threadIdx.x & 63;
  int lm = l & 15, lq = l >> 4;
  int p0 = blockIdx.x * 32 + wv * 16;
  int co0 = blockIdx.y * 16;
  int t = blockIdx.z;
  int p = p0 + lm;
  int px = p & 63, py = p >> 6;

  float bv = bias[t * 64 + co0 + lm];
  f32x4 acc = (f32x4){bv, bv, bv, bv};
  const unsigned short* wp = Wm + ((size_t)t * 64 + co0 + lm) * 576 + lq * 8;
#pragma unroll
  for (int kidx = 0; kidx < 9; kidx++) {
    int ky = kidx / 3, kx = kidx % 3;
    int pp = p + (ky - 1) * 64 + (kx - 1);
    bool valid = ((unsigned)(px + kx - 1) < 64u) && ((unsigned)(py + ky - 1) < 64u);
    const unsigned short* apb = h + (size_t)pp * 192 + t * 64 + lq * 8;
#pragma unroll
    for (int c2 = 0; c2 < 2; c2++) {
      short8 af = {};
      if (valid) af = *(const short8*)(apb + c2 * 32);
      short8 bf = *(const short8*)(wp + kidx * 64 + c2 * 32);
      acc = __builtin_amdgcn_mfma_f32_16x16x32_bf16(af, bf, acc, 0, 0, 0);
    }
  }
#pragma unroll
  for (int r = 0; r < 4; r++) {
    int po_ = p0 + lq * 4 + r;
    out[(size_t)po_ * 192 + t * 64 + co0 + lm] = f2bf(lrelu_f(acc[r]));
  }
}

// Fused conv3 (h2 -> h3 in LDS) + tail GEMM (+exp/sigmoid epilogue) -> to [p][3456].
// Block = 128 thr (2 waves), 16 pixels. k_tail's GEMM is per-pixel local in h3,
// so fusing removes the h3 buffer + one dispatch entirely.
__global__ __launch_bounds__(128) void k_c3tail(const unsigned short* __restrict__ h2,
                                                const unsigned short* __restrict__ W3g,
                                                const float* __restrict__ b3c,
                                                const unsigned short* __restrict__ Wtail,
                                                const float* __restrict__ btail,
                                                unsigned short* __restrict__ to) {
  __shared__ unsigned short h3L[16 * 200];   // row padded to 200 shorts (16B-aligned rows)
  int tid = threadIdx.x;
  int wv = tid >> 6;
  int l = tid & 63;
  int lm = l & 15, lq = l >> 4;
  int p0 = blockIdx.x * 16;
  int p = p0 + lm;
  int px = p & 63, py = p >> 6;

  // Stage 1: grouped 3x3 conv; wave wv covers 6 co-tiles (96 channels)
#pragma unroll 1
  for (int ct = 0; ct < 6; ct++) {
    int gco = wv * 96 + ct * 16;     // global col 0..191
    int t = gco >> 6;
    float bv = b3c[gco + lm];
    f32x4 acc = (f32x4){bv, bv, bv, bv};
    const unsigned short* wp = W3g + (size_t)(gco + lm) * 576 + lq * 8;
#pragma unroll
    for (int kidx = 0; kidx < 9; kidx++) {
      int ky = kidx / 3, kx = kidx % 3;
      int pp = p + (ky - 1) * 64 + (kx - 1);
      bool valid = ((unsigned)(px + kx - 1) < 64u) && ((unsigned)(py + ky - 1) < 64u);
      const unsigned short* apb = h2 + (size_t)pp * 192 + t * 64 + lq * 8;
#pragma unroll
      for (int c2 = 0; c2 < 2; c2++) {
        short8 af = {};
        if (valid) af = *(const short8*)(apb + c2 * 32);
        short8 bf = *(const short8*)(wp + kidx * 64 + c2 * 32);
        acc = __builtin_amdgcn_mfma_f32_16x16x32_bf16(af, bf, acc, 0, 0, 0);
      }
    }
#pragma unroll
    for (int r = 0; r < 4; r++)
      h3L[(lq * 4 + r) * 200 + gco + lm] = f2bf(lrelu_f(acc[r]));
  }
  __syncthreads();

  // Stage 2: tail GEMM from LDS; wave wv covers co in [wv*1728, (wv+1)*1728)
#pragma unroll 1
  for (int ti = 0; ti < 54; ti++) {
    int co0 = wv * 1728 + ti * 32;
    int t = (co0 < 576) ? 0 : (co0 < 864 ? 1 : 2);
    f32x4 acc[2];
#pragma unroll
    for (int nt = 0; nt < 2; nt++) {
      float bv = btail[co0 + nt * 16 + lm];
      acc[nt] = (f32x4){bv, bv, bv, bv};
    }
    const unsigned short* ap = h3L + lm * 200 + t * 64 + lq * 8;
    const unsigned short* wp = Wtail + (size_t)(co0 + lm) * 64 + lq * 8;
#pragma unroll
    for (int k0 = 0; k0 < 64; k0 += 32) {
      short8 af = *(const short8*)(ap + k0);
#pragma unroll
      for (int nt = 0; nt < 2; nt++) {
        short8 bf = *(const short8*)(wp + (size_t)nt * 16 * 64 + k0);
        acc[nt] = __builtin_amdgcn_mfma_f32_16x16x32_bf16(af, bf, acc[nt], 0, 0, 0);
      }
    }
#pragma unroll
    for (int nt = 0; nt < 2; nt++) {
      int co = co0 + nt * 16 + lm;
#pragma unroll
      for (int r = 0; r < 4; r++) {
        int pw = p0 + lq * 4 + r;
        float v = acc[nt][r];
        if (t == 2) v = __expf(v);                                            // aw -> exp(logit)
        else if (t == 1) v = 3.f * __builtin_amdgcn_rcpf(1.f + __expf(-v));   // po -> 3*sigmoid
        to[(size_t)pw * 3456 + co] = f2bf(v);
      }
    }
  }
}

// Fused softmax + deformable sampling + output convs + residual.
// Block = 256 thr = 2 pixels x 8 heads x 16 lanes (R14 version, 3456-short rows).
__global__ __launch_bounds__(256, 4) void k_msdout(
    const unsigned char* __restrict__ v8,
    const unsigned short* __restrict__ to,
    const float* __restrict__ flow1, const float* __restrict__ fcn2,
    const unsigned short* __restrict__ o1b, const float* __restrict__ bias1,
    const unsigned short* __restrict__ o2b, const float* __restrict__ bias2,
    const float* __restrict__ x, float* __restrict__ out) {
  __shared__ float featL[2][64];
  __shared__ float hopL[2][64];
  int tid = threadIdx.x;
  int yl = tid & 15;
  int m = (tid >> 4) & 7;
  int pl = tid >> 7;
  int p = blockIdx.x * 2 + pl;
  int px = p & 63, py = p >> 6;

  float fx1 = flow1[p], fy1 = flow1[HWN + p];
  float fx2 = fcn2[p],  fy2 = fcn2[HWN + p];

  const unsigned short* row = to + (size_t)p * 3456;

  f32x2 accv[4];
#pragma unroll
  for (int d = 0; d < 4; d++) accv[d] = (f32x2){0.f, 0.f};
  float wsum = 0.f;

#pragma unroll 1
  for (int pair = yl; pair < 36; pair += 16) {
    int lv = pair / 12, pt = pair % 12;
    float fx = (lv == 1) ? fx1 : ((lv == 2) ? fx2 : 0.f);
    float fy = (lv == 1) ? fy1 : ((lv == 2) ? fy2 : 0.f);
    int ch = (m * 3 + lv) * 12 + pt;
    unsigned ow = *(const unsigned*)(row + ch * 2);
    float ox = bf_lo(ow);
    float oy = bf_hi(ow);
    float s = bf2f(row[576 + ch]);         // pre-transformed: 3*sigmoid(po)
    float bx = (float)px + ox + fx;
    float by = (float)py + oy + fy;
    int lmoff = (lv * 8 + m) * (VYP * VROW * 16);
    const unsigned short* lgp = row + 864 + m * 324 + lv * 108 + pt * 9;

    // y-side precompute (constant indices after unroll)
    const unsigned char* rb[3];
    float yw0[3], yw1[3];
#pragma unroll
    for (int j = 0; j < 3; j++) {
      float cy = by + (float)(j - 1) * s;
      float fy0 = floorf(cy);
      yw1[j] = cy - fy0; yw0[j] = 1.f - yw1[j];
      int y0 = min(max((int)fy0, -2), 66);
      int par = y0 & 1;
      int yp = (y0 + 2 - par) >> 1;
      rb[j] = v8 + par * VSZ_B + lmoff + yp * (VROW * 16);
    }
#pragma unroll 1
    for (int jx = 0; jx < 3; jx++) {
      float cx = bx + (float)(jx - 1) * s;
      float fx0 = floorf(cx);
      float wx1 = cx - fx0, wx0 = 1.f - wx1;
      int xoff = (min(max((int)fx0, -2), 66) + 2) * 16;
      const unsigned short* lg3 = lgp + jx * 3;
#pragma unroll
      for (int jy = 0; jy < 3; jy++) {
        float wgt = bf2f(lg3[jy]);         // pre-transformed: exp(logit)
        wsum += wgt;
        const unsigned char* vb = rb[jy] + xoff;
        uint4 qa = *(const uint4*)vb;        // x0:   [slot0 8ch][slot1 8ch]
        uint4 qb = *(const uint4*)(vb + 16); // x0+1

        float w00 = wgt * wx0 * yw0[jy], w01 = wgt * wx0 * yw1[jy];
        float w10 = wgt * wx1 * yw0[jy], w11 = wgt * wx1 * yw1[jy];
        f32x2 W00 = (f32x2){w00, w00}, W01 = (f32x2){w01, w01};
        f32x2 W10 = (f32x2){w10, w10}, W11 = (f32x2){w11, w11};

        accv[0] += W00 * cvt8<false>(qa.x) + W01 * cvt8<false>(qa.z)
                 + W10 * cvt8<false>(qb.x) + W11 * cvt8<false>(qb.z);
        accv[1] += W00 * cvt8<true>(qa.x)  + W01 * cvt8<true>(qa.z)
                 + W10 * cvt8<true>(qb.x)  + W11 * cvt8<true>(qb.z);
        accv[2] += W00 * cvt8<false>(qa.y) + W01 * cvt8<false>(qa.w)
                 + W10 * cvt8<false>(qb.y) + W11 * cvt8<false>(qb.w);
        accv[3] += W00 * cvt8<true>(qa.y)  + W01 * cvt8<true>(qa.w)
                 + W10 * cvt8<true>(qb.y)  + W11 * cvt8<true>(qb.w);
      }
    }
  }
#pragma unroll
  for (int mask = 1; mask < 16; mask <<= 1) {
    wsum += __shfl_xor(wsum, mask);
#pragma unroll
    for (int d = 0; d < 4; d++) {
      accv[d].x += __shfl_xor(accv[d].x, mask);
      accv[d].y += __shfl_xor(accv[d].y, mask);
    }
  }
  if (yl < 8) {
    float inv = __builtin_amdgcn_rcpf(wsum);
    float r = 0.f;
#pragma unroll
    for (int d = 0; d < 8; d++) {
      float v = (d & 1) ? accv[d >> 1].y : accv[d >> 1].x;
      r = (d == yl) ? v : r;
    }
    featL[pl][m * 8 + yl] = r * inv;
  }
  __syncthreads();

  // output conv stage 1: hop = lrelu(W1·feat + b1)
  if (tid < 128) {
    int ql = tid >> 6, co = tid & 63;
    float a = bias1[co];
    const uint4* wr = (const uint4*)(o1b + co * 64);
#pragma unroll
    for (int c8 = 0; c8 < 8; c8++) {
      uint4 wv = wr[c8];
      int ci = c8 * 8;
      a += bf_lo(wv.x) * featL[ql][ci]     + bf_hi(wv.x) * featL[ql][ci + 1]
         + bf_lo(wv.y) * featL[ql][ci + 2] + bf_hi(wv.y) * featL[ql][ci + 3]
         + bf_lo(wv.z) * featL[ql][ci + 4] + bf_hi(wv.z) * featL[ql][ci + 5]
         + bf_lo(wv.w) * featL[ql][ci + 6] + bf_hi(wv.w) * featL[ql][ci + 7];
    }
    hopL[ql][co] = lrelu_f(a);
  }
  __syncthreads();

  // output conv stage 2 + residual
  if (tid < 128) {
    int ql = tid >> 6, co = tid & 63;
    int p2 = blockIdx.x * 2 + ql;
    float a = bias2[co];
    const uint4* wr = (const uint4*)(o2b + co * 64);
#pragma unroll
    for (int c8 = 0; c8 < 8; c8++) {
      uint4 wv = wr[c8];
      int ci = c8 * 8;
      a += bf_lo(wv.x) * hopL[ql][ci]     + bf_hi(wv.x) * hopL[ql][ci + 1]
         + bf_lo(wv.y) * hopL[ql][ci + 2] + bf_hi(wv.y) * hopL[ql][ci + 3]
         + bf_lo(wv.z) * hopL[ql][ci + 4] + bf_hi(wv.z) * hopL[ql][ci + 5]
         + bf_lo(wv.w) * hopL[ql][ci + 6] + bf_hi(wv.w) * hopL[ql][ci + 7];
    }
    out[(size_t)co * HWN + p2] = a + x[(size_t)co * HWN + p2];
  }
}

extern "C" void kernel_launch(void* const* d_in, const int* in_sizes, int n_in,
                              void* d_out, int out_size, void* d_ws, size_t ws_size,
                              hipStream_t stream) {
  const float* x     = (const float*)d_in[0];
  const float* flow1 = (const float*)d_in[1];
  const float* flow2 = (const float*)d_in[2];
  const float* aw_w1 = (const float*)d_in[5];
  const float* aw_b1 = (const float*)d_in[6];
  const float* aw_w2 = (const float*)d_in[7];
  const float* aw_b2 = (const float*)d_in[8];
  const float* aw_w3 = (const float*)d_in[9];
  const float* aw_b3 = (const float*)d_in[10];
  const float* aw_w4 = (const float*)d_in[11];
  const float* aw_b4 = (const float*)d_in[12];
  const float* so_w1 = (const float*)d_in[13];
  const float* so_b1 = (const float*)d_in[14];
  const float* so_w2 = (const float*)d_in[15];
  const float* so_b2 = (const float*)d_in[16];
  const float* so_w3 = (const float*)d_in[17];
  const float* so_b3 = (const float*)d_in[18];
  const float* so_w4 = (const float*)d_in[19];
  const float* so_b4 = (const float*)d_in[20];
  const float* po_w1 = (const float*)d_in[21];
  const float* po_b1 = (const float*)d_in[22];
  const float* po_w2 = (const float*)d_in[23];
  const float* po_b2 = (const float*)d_in[24];
  const float* po_w3 = (const float*)d_in[25];
  const float* po_b3 = (const float*)d_in[26];
  const float* po_w4 = (const float*)d_in[27];
  const float* po_b4 = (const float*)d_in[28];
  const float* vp_w  = (const float*)d_in[29];
  const float* vp_b  = (const float*)d_in[30];
  const float* op_w1 = (const float*)d_in[31];
  const float* op_b1 = (const float*)d_in[32];
  const float* op_w2 = (const float*)d_in[33];
  const float* op_b2 = (const float*)d_in[34];

  char* base = (char*)d_ws;
  size_t off = 0;
  auto alloc = [&](size_t bytes) { void* pp = base + off; off = (off + bytes + 255) & ~(size_t)255; return pp; };

  float* fcn2  = (float*)alloc(2 * HWN * 4);
  unsigned short* xb    = (unsigned short*)alloc(192 * HWN * 2);
  unsigned short* vsb   = (unsigned short*)alloc(192 * HWN * 2);
  unsigned short* extra = (unsigned short*)alloc(224 * HWN * 2);
  unsigned short* h1    = (unsigned short*)alloc(192 * HWN * 2);
  unsigned short* h2    = (unsigned short*)alloc(192 * HWN * 2);
  unsigned short* to    = (unsigned short*)alloc((size_t)3456 * HWN * 2);
  unsigned char* v8     = (unsigned char*)alloc((size_t)VSZ_B * 2);
  unsigned short* Wtail = (unsigned short*)alloc(3456 * 64 * 2);
  float* btail = (float*)alloc(3456 * 4);
  float* b1c   = (float*)alloc(192 * 4);
  float* b2c   = (float*)alloc(192 * 4);
  float* b3c   = (float*)alloc(192 * 4);
  unsigned short* o1b = (unsigned short*)alloc(64 * 64 * 2);
  unsigned short* o2b = (unsigned short*)alloc(64 * 64 * 2);
  unsigned short* W1  = (unsigned short*)alloc(192 * 224 * 2);
  unsigned short* W2g = (unsigned short*)alloc(3 * 64 * 576 * 2);
  unsigned short* W3g = (unsigned short*)alloc(3 * 64 * 576 * 2);
  unsigned short* vpb = (unsigned short*)alloc(192 * 192 * 2);

  k_pre<<<2302, 256, 0, stream>>>(
      x, flow1, flow2,
      so_w4, po_w4, aw_w4, so_b4, po_b4, aw_b4,
      so_b1, po_b1, aw_b1, so_b2, po_b2, aw_b2, so_b3, po_b3, aw_b3,
      so_w1, po_w1, aw_w1, so_w2, po_w2, aw_w2, so_w3, po_w3, aw_w3,
      op_w1, op_w2, vp_w,
      Wtail, btail, b1c, b2c, b3c, o1b, o2b, W1, W2g, W3g, vpb, xb, fcn2, v8);

  k_extra<<<1024, 256, 0, stream>>>(xb, flow1, fcn2, extra);

  // z=0: value proj xb->vsb; z=1: trunk head extra->h1
  k_gemm2<<<dim3(128, 6, 2), 128, 0, stream>>>(xb, vpb, vp_b, vsb, extra, W1, b1c, h1);

  // z<3: grouped conv h1->h2; z==3: vsb -> fp8 repack
  k_conv3g<<<dim3(128, 4, 4), 128, 0, stream>>>(h1, W2g, b2c, h2, vsb, v8);

  // fused conv3 + tail GEMM -> to
  k_c3tail<<<256, 128, 0, stream>>>(h2, W3g, b3c, Wtail, btail, to);

  // fused sampling + softmax + output convs + residual
  k_msdout<<<2048, 256, 0, stream>>>(v8, to, flow1, fcn2, o1b, op_b1, o2b, op_b2, x, (float*)d_out);
}

// Round 17
// 227.923 us; speedup vs baseline: 1.1272x; 1.1272x over previous
//
#include <hip/hip_runtime.h>
#include <hip/hip_bf16.h>
#include <math.h>

// n=1, t=3(=L), c=64, h=w=64, M=8, D=8, P=12, KK=9
#define HWN 4096
// fp8 dual-copy value layout: [24 lm][36 yp][72 x][2 slot][8 ch] BYTES
#define VROW 72
#define VYP 36
#define VSZ_B (24 * VYP * VROW * 16)   // 995328 bytes per copy

typedef __attribute__((ext_vector_type(8))) short short8;
typedef __attribute__((ext_vector_type(4))) float f32x4;
typedef __attribute__((ext_vector_type(2))) float f32x2;

__device__ __forceinline__ float lrelu_f(float v) { return v >= 0.f ? v : 0.1f * v; }

__device__ __forceinline__ unsigned short f2bf(float f) {
  union { float f; unsigned u; } v; v.f = f;
  unsigned r = v.u + 0x7fff + ((v.u >> 16) & 1);   // round-to-nearest-even
  return (unsigned short)(r >> 16);
}
__device__ __forceinline__ float bf2f(unsigned short u) {
  union { unsigned u; float f; } v; v.u = ((unsigned)u) << 16; return v.f;
}
__device__ __forceinline__ float bf_lo(unsigned u) {
  union { unsigned u; float f; } v; v.u = u << 16; return v.f;
}
__device__ __forceinline__ float bf_hi(unsigned u) {
  union { unsigned u; float f; } v; v.u = u & 0xffff0000u; return v.f;
}
// word-select must be an immediate constant -> template parameter
template <bool HI>
__device__ __forceinline__ f32x2 cvt8(unsigned u) {
  return __builtin_amdgcn_cvt_pk_f32_fp8((int)u, HI);
}

__device__ __forceinline__ float bilin_zero(const float* __restrict__ img, float ix, float iy) {
  float fx0 = floorf(ix), fy0 = floorf(iy);
  int x0 = (int)fx0, y0 = (int)fy0;
  float wx1 = ix - fx0, wy1 = iy - fy0;
  float wx0 = 1.f - wx1, wy0 = 1.f - wy1;
  float acc = 0.f;
  if ((unsigned)y0 < 64u) {
    if ((unsigned)x0 < 64u)       acc += wx0 * wy0 * img[y0 * 64 + x0];
    if ((unsigned)(x0 + 1) < 64u) acc += wx1 * wy0 * img[y0 * 64 + x0 + 1];
  }
  if ((unsigned)(y0 + 1) < 64u) {
    if ((unsigned)x0 < 64u)       acc += wx0 * wy1 * img[(y0 + 1) * 64 + x0];
    if ((unsigned)(x0 + 1) < 64u) acc += wx1 * wy1 * img[(y0 + 1) * 64 + x0 + 1];
  }
  return acc;
}

// k_pre segments (by blockIdx.x):
// [0,864) Wtail | [864,912) biases+op | [912,1080) W1 | [1080,1464) W2g/W3g
// [1464,1608) vpb | [1608,1800) x transpose | [1800,1816) flow_cn2
// [1816,2302) zero v8 (fp8, 2*VSZ_B bytes)
__global__ void k_pre(
    const float* __restrict__ x, const float* __restrict__ flow1, const float* __restrict__ flow2,
    const float* so_w4, const float* po_w4, const float* aw_w4,
    const float* so_b4, const float* po_b4, const float* aw_b4,
    const float* so_b1, const float* po_b1, const float* aw_b1,
    const float* so_b2, const float* po_b2, const float* aw_b2,
    const float* so_b3, const float* po_b3, const float* aw_b3,
    const float* so_w1, const float* po_w1, const float* aw_w1,
    const float* so_w2, const float* po_w2, const float* aw_w2,
    const float* so_w3, const float* po_w3, const float* aw_w3,
    const float* op_w1, const float* op_w2, const float* vp_w,
    unsigned short* Wtail, float* btail, float* b1c, float* b2c, float* b3c,
    unsigned short* o1b, unsigned short* o2b, unsigned short* W1,
    unsigned short* W2g, unsigned short* W3g, unsigned short* vpb,
    unsigned short* xb, float* fcn2, unsigned char* v8) {
  __shared__ unsigned short tile[64 * 65];
  __shared__ unsigned short wrow[576];
  int gx = blockIdx.x;
  int tid = threadIdx.x;
  if (gx < 864) {  // Wtail [3456][64]
    int t = gx * 256 + tid;
    int row = t >> 6, k = t & 63;
    float v = row < 576 ? so_w4[row * 64 + k]
            : row < 864 ? po_w4[(row - 576) * 64 + k]
                        : aw_w4[(row - 864) * 64 + k];
    Wtail[t] = f2bf(v);
  } else if (gx < 912) {
    int t = (gx - 864) * 256 + tid;
    if (t < 3456) {
      btail[t] = t < 576 ? so_b4[t] : t < 864 ? po_b4[t - 576] : aw_b4[t - 864];
    } else if (t < 3648) {
      int i = t - 3456; b1c[i] = i < 64 ? so_b1[i] : i < 128 ? po_b1[i - 64] : aw_b1[i - 128];
    } else if (t < 3840) {
      int i = t - 3648; b2c[i] = i < 64 ? so_b2[i] : i < 128 ? po_b2[i - 64] : aw_b2[i - 128];
    } else if (t < 4032) {
      int i = t - 3840; b3c[i] = i < 64 ? so_b3[i] : i < 128 ? po_b3[i - 64] : aw_b3[i - 128];
    } else if (t < 8128) {
      o1b[t - 4032] = f2bf(op_w1[t - 4032]);
    } else if (t < 12224) {
      o2b[t - 8128] = f2bf(op_w2[t - 8128]);
    }
  } else if (gx < 1080) {  // W1 [192][224] zero-padded K
    int t = (gx - 912) * 256 + tid;
    if (t < 192 * 224) {
      int row = t / 224, k = t % 224;
      int tr = row >> 6, lco = row & 63;
      const float* s = tr == 0 ? so_w1 : tr == 1 ? po_w1 : aw_w1;
      W1[t] = (k < 196) ? f2bf(s[lco * 196 + k]) : (unsigned short)0;
    }
  } else if (gx < 1464) {  // W2g/W3g LDS transpose
    int b = gx - 1080;
    int which = b >= 192;
    b &= 191;
    int tr = b >> 6, co = b & 63;
    const float* s;
    if (!which) s = tr == 0 ? so_w2 : tr == 1 ? po_w2 : aw_w2;
    else        s = tr == 0 ? so_w3 : tr == 1 ? po_w3 : aw_w3;
    unsigned short* d = which ? W3g : W2g;
#pragma unroll
    for (int j = tid; j < 576; j += 256) wrow[j] = f2bf(s[co * 576 + j]);
    __syncthreads();
#pragma unroll
    for (int j = tid; j < 576; j += 256)
      d[((size_t)tr * 64 + co) * 576 + j] = wrow[(j & 63) * 9 + (j >> 6)];
  } else if (gx < 1608) {  // vpb [192][192]
    int t = (gx - 1464) * 256 + tid;
    if (t < 192 * 192) vpb[t] = f2bf(vp_w[t]);
  } else if (gx < 1800) {  // x transpose -> xb [p][192]
    int b = gx - 1608;
    int ptile = b & 63, cg = b >> 6;  // 64 x 3
    int px = tid & 63, ch0 = (tid >> 6) * 16;
#pragma unroll
    for (int i = 0; i < 16; i++) {
      float v = x[(size_t)(cg * 64 + ch0 + i) * HWN + ptile * 64 + px];
      tile[(ch0 + i) * 65 + px] = f2bf(v);
    }
    __syncthreads();
    int c = tid & 63, pl0 = (tid >> 6) * 16;
#pragma unroll
    for (int i = 0; i < 16; i++)
      xb[(size_t)(ptile * 64 + pl0 + i) * 192 + cg * 64 + c] = tile[c * 65 + pl0 + i];
  } else if (gx < 1816) {  // flow_cn2
    int p = (gx - 1800) * 256 + tid;
    int px = p & 63, py = p >> 6;
    float fx = flow1[p], fy = flow1[HWN + p];
    float ix = (float)px + fx, iy = (float)py + fy;
    fcn2[p] = fx + bilin_zero(flow2, ix, iy);
    fcn2[HWN + p] = fy + bilin_zero(flow2 + HWN, ix, iy);
  } else {  // zero fp8 tables: 2*VSZ_B/16 = 124416 uint4
    int i = (gx - 1816) * 256 + tid;
    if (i < 2 * VSZ_B / 16) ((uint4*)v8)[i] = make_uint4(0, 0, 0, 0);
  }
}

// k_extra: wave per pixel, lane = channel. All accesses coalesced.
__global__ void k_extra(const unsigned short* __restrict__ xb, const float* __restrict__ flow1,
                        const float* __restrict__ fcn2, unsigned short* __restrict__ extra) {
  int w = threadIdx.x >> 6, c = threadIdx.x & 63;
  int p = blockIdx.x * 4 + w;
  int px = p & 63, py = p >> 6;
  float fx1 = flow1[p], fy1 = flow1[HWN + p];
  float fx2 = fcn2[p],  fy2 = fcn2[HWN + p];
  extra[(size_t)p * 224 + c] = xb[(size_t)p * 192 + c];
#pragma unroll
  for (int lev = 0; lev < 2; lev++) {
    float ix = (float)px + (lev ? fx2 : fx1);
    float iy = (float)py + (lev ? fy2 : fy1);
    float fx0 = floorf(ix), fy0 = floorf(iy);
    int x0 = (int)fx0, y0 = (int)fy0;
    float wx1 = ix - fx0, wy1 = iy - fy0;
    float wx0 = 1.f - wx1, wy0 = 1.f - wy1;
    int coff = (lev + 1) * 64;
    float acc = 0.f;
    if ((unsigned)y0 < 64u) {
      if ((unsigned)x0 < 64u)       acc += wx0 * wy0 * bf2f(xb[(size_t)(y0 * 64 + x0) * 192 + coff + c]);
      if ((unsigned)(x0 + 1) < 64u) acc += wx1 * wy0 * bf2f(xb[(size_t)(y0 * 64 + x0 + 1) * 192 + coff + c]);
    }
    if ((unsigned)(y0 + 1) < 64u) {
      if ((unsigned)x0 < 64u)       acc += wx0 * wy1 * bf2f(xb[(size_t)((y0 + 1) * 64 + x0) * 192 + coff + c]);
      if ((unsigned)(x0 + 1) < 64u) acc += wx1 * wy1 * bf2f(xb[(size_t)((y0 + 1) * 64 + x0 + 1) * 192 + coff + c]);
    }
    extra[(size_t)p * 224 + coff + c] = f2bf(acc);
  }
  if (c < 2) {
    extra[(size_t)p * 224 + 192 + c] = f2bf(flow1[c * HWN + p]);
    extra[(size_t)p * 224 + 194 + c] = f2bf(fcn2[c * HWN + p]);
  }
  if (c < 28) extra[(size_t)p * 224 + 196 + c] = 0;
}

// Two GEMMs in one dispatch (blockIdx.z): z=0 value-proj (K=192), z=1 trunk head (K=224, lrelu).
__global__ __launch_bounds__(128) void k_gemm2(
    const unsigned short* __restrict__ A0, const unsigned short* __restrict__ Wm0,
    const float* __restrict__ bias0, unsigned short* __restrict__ out0,
    const unsigned short* __restrict__ A1, const unsigned short* __restrict__ Wm1,
    const float* __restrict__ bias1, unsigned short* __restrict__ out1) {
  int z = blockIdx.z;
  const unsigned short* A = z ? A1 : A0;
  const unsigned short* Wm = z ? Wm1 : Wm0;
  const float* bias = z ? bias1 : bias0;
  unsigned short* out = z ? out1 : out0;
  int K = z ? 224 : 192;

  int wv = threadIdx.x >> 6;
  int l = threadIdx.x & 63;
  int lm = l & 15, lq = l >> 4;
  int p0 = blockIdx.x * 32 + wv * 16;
  int co0 = blockIdx.y * 32;

  f32x4 acc[2];
#pragma unroll
  for (int nt = 0; nt < 2; nt++) {
    float bv = bias[co0 + nt * 16 + lm];
    acc[nt] = (f32x4){bv, bv, bv, bv};
  }
  const unsigned short* ap = A + (size_t)(p0 + lm) * K + lq * 8;
  const unsigned short* wp = Wm + (size_t)(co0 + lm) * K + lq * 8;
  for (int k0 = 0; k0 < K; k0 += 32) {
    short8 af = *(const short8*)(ap + k0);
#pragma unroll
    for (int nt = 0; nt < 2; nt++) {
      short8 bf = *(const short8*)(wp + (size_t)nt * 16 * K + k0);
      acc[nt] = __builtin_amdgcn_mfma_f32_16x16x32_bf16(af, bf, acc[nt], 0, 0, 0);
    }
  }
#pragma unroll
  for (int nt = 0; nt < 2; nt++) {
    int co = co0 + nt * 16 + lm;
#pragma unroll
    for (int r = 0; r < 4; r++) {
      int p = p0 + lq * 4 + r;
      float v = acc[nt][r];
      if (z) v = lrelu_f(v);
      out[(size_t)p * 192 + co] = f2bf(v);
    }
  }
}

// Grouped direct 3x3 conv (pad 1); z==3 plane (first call only): fp8 value repack.
__global__ __launch_bounds__(128) void k_conv3g(const unsigned short* __restrict__ h,
                                                const unsigned short* __restrict__ Wm,
                                                const float* __restrict__ bias,
                                                unsigned short* __restrict__ out,
                                                const unsigned short* __restrict__ vsb,
                                                unsigned char* __restrict__ v8) {
  if (blockIdx.z == 3) {  // repack vsb [p][192] bf16 -> fp8 dual copies
    int b = blockIdx.y * 128 + blockIdx.x;   // 0..511
    int i = b * 128 + threadIdx.x;           // 0..65535
#pragma unroll
    for (int rep = 0; rep < 2; rep++, i += 65536) {
      if (i < 98304) {
        int lm = i % 24, p = i / 24;
        uint4 vv = ((const uint4*)vsb)[p * 24 + lm];
        int lo = 0, hi = 0;
        lo = __builtin_amdgcn_cvt_pk_fp8_f32(bf_lo(vv.x), bf_hi(vv.x), lo, false);
        lo = __builtin_amdgcn_cvt_pk_fp8_f32(bf_lo(vv.y), bf_hi(vv.y), lo, true);
        hi = __builtin_amdgcn_cvt_pk_fp8_f32(bf_lo(vv.z), bf_hi(vv.z), hi, false);
        hi = __builtin_amdgcn_cvt_pk_fp8_f32(bf_lo(vv.w), bf_hi(vv.w), hi, true);
        uint2 pk; pk.x = (unsigned)lo; pk.y = (unsigned)hi;
        int y = p >> 6, xx = p & 63;
        int ypA = (y >> 1) + 1, slotA = y & 1;
        int ypB = (y + 1) >> 1, slotB = (y & 1) ^ 1;
        *(uint2*)(v8 + (((lm * VYP + ypA) * VROW + xx + 2) * 16 + slotA * 8)) = pk;
        *(uint2*)(v8 + VSZ_B + (((lm * VYP + ypB) * VROW + xx + 2) * 16 + slotB * 8)) = pk;
      }
    }
    return;
  }
  int wv = threadIdx.x >> 6;
  int l = threadIdx.x & 63;
  int lm = l & 15, lq = l >> 4;
  int p0 = blockIdx.x * 32 + wv * 16;
  int co0 = blockIdx.y * 16;
  int t = blockIdx.z;
  int p = p0 + lm;
  int px = p & 63, py = p >> 6;

  float bv = bias[t * 64 + co0 + lm];
  f32x4 acc = (f32x4){bv, bv, bv, bv};
  const unsigned short* wp = Wm + ((size_t)t * 64 + co0 + lm) * 576 + lq * 8;
#pragma unroll
  for (int kidx = 0; kidx < 9; kidx++) {
    int ky = kidx / 3, kx = kidx % 3;
    int pp = p + (ky - 1) * 64 + (kx - 1);
    bool valid = ((unsigned)(px + kx - 1) < 64u) && ((unsigned)(py + ky - 1) < 64u);
    const unsigned short* apb = h + (size_t)pp * 192 + t * 64 + lq * 8;
#pragma unroll
    for (int c2 = 0; c2 < 2; c2++) {
      short8 af = {};
      if (valid) af = *(const short8*)(apb + c2 * 32);
      short8 bf = *(const short8*)(wp + kidx * 64 + c2 * 32);
      acc = __builtin_amdgcn_mfma_f32_16x16x32_bf16(af, bf, acc, 0, 0, 0);
    }
  }
#pragma unroll
  for (int r = 0; r < 4; r++) {
    int po_ = p0 + lq * 4 + r;
    out[(size_t)po_ * 192 + t * 64 + co0 + lm] = f2bf(lrelu_f(acc[r]));
  }
}

// k_tail: trunk 1x1 tails (+exp/3*sigmoid epilogue) -> to [p][3456].
__global__ __launch_bounds__(256) void k_tail(const unsigned short* __restrict__ A,
                                              const unsigned short* __restrict__ Wm,
                                              const float* __restrict__ bias,
                                              unsigned short* __restrict__ out) {
  int wv = threadIdx.x >> 6;
  int l = threadIdx.x & 63;
  int lm = l & 15, lq = l >> 4;
  int p0 = blockIdx.x * 64 + wv * 16;
  int co0 = blockIdx.y * 32;
  int t = (co0 < 576) ? 0 : (co0 < 864 ? 1 : 2);

  f32x4 acc[2];
#pragma unroll
  for (int nt = 0; nt < 2; nt++) {
    float bv = bias[co0 + nt * 16 + lm];
    acc[nt] = (f32x4){bv, bv, bv, bv};
  }
  const unsigned short* ap = A + (size_t)(p0 + lm) * 192 + t * 64 + lq * 8;
  const unsigned short* wp = Wm + (size_t)(co0 + lm) * 64 + lq * 8;
#pragma unroll
  for (int k0 = 0; k0 < 64; k0 += 32) {
    short8 af = *(const short8*)(ap + k0);
#pragma unroll
    for (int nt = 0; nt < 2; nt++) {
      short8 bf = *(const short8*)(wp + (size_t)nt * 16 * 64 + k0);
      acc[nt] = __builtin_amdgcn_mfma_f32_16x16x32_bf16(af, bf, acc[nt], 0, 0, 0);
    }
  }
#pragma unroll
  for (int nt = 0; nt < 2; nt++) {
    int co = co0 + nt * 16 + lm;
#pragma unroll
    for (int r = 0; r < 4; r++) {
      int p = p0 + lq * 4 + r;
      float v = acc[nt][r];
      if (t == 2) v = __expf(v);                                            // aw -> exp(logit)
      else if (t == 1) v = 3.f * __builtin_amdgcn_rcpf(1.f + __expf(-v));   // po -> 3*sigmoid
      out[(size_t)p * 3456 + co] = f2bf(v);
    }
  }
}

// Fused softmax + deformable sampling + output convs + residual.
// Block = 256 thr = 2 pixels x 8 heads x 16 lanes (R14 version).
__global__ __launch_bounds__(256, 4) void k_msdout(
    const unsigned char* __restrict__ v8,
    const unsigned short* __restrict__ to,
    const float* __restrict__ flow1, const float* __restrict__ fcn2,
    const unsigned short* __restrict__ o1b, const float* __restrict__ bias1,
    const unsigned short* __restrict__ o2b, const float* __restrict__ bias2,
    const float* __restrict__ x, float* __restrict__ out) {
  __shared__ float featL[2][64];
  __shared__ float hopL[2][64];
  int tid = threadIdx.x;
  int yl = tid & 15;
  int m = (tid >> 4) & 7;
  int pl = tid >> 7;
  int p = blockIdx.x * 2 + pl;
  int px = p & 63, py = p >> 6;

  float fx1 = flow1[p], fy1 = flow1[HWN + p];
  float fx2 = fcn2[p],  fy2 = fcn2[HWN + p];

  const unsigned short* row = to + (size_t)p * 3456;

  f32x2 accv[4];
#pragma unroll
  for (int d = 0; d < 4; d++) accv[d] = (f32x2){0.f, 0.f};
  float wsum = 0.f;

#pragma unroll 1
  for (int pair = yl; pair < 36; pair += 16) {
    int lv = pair / 12, pt = pair % 12;
    float fx = (lv == 1) ? fx1 : ((lv == 2) ? fx2 : 0.f);
    float fy = (lv == 1) ? fy1 : ((lv == 2) ? fy2 : 0.f);
    int ch = (m * 3 + lv) * 12 + pt;
    unsigned ow = *(const unsigned*)(row + ch * 2);
    float ox = bf_lo(ow);
    float oy = bf_hi(ow);
    float s = bf2f(row[576 + ch]);         // pre-transformed: 3*sigmoid(po)
    float bx = (float)px + ox + fx;
    float by = (float)py + oy + fy;
    int lmoff = (lv * 8 + m) * (VYP * VROW * 16);
    const unsigned short* lgp = row + 864 + m * 324 + lv * 108 + pt * 9;

    // y-side precompute (constant indices after unroll)
    const unsigned char* rb[3];
    float yw0[3], yw1[3];
#pragma unroll
    for (int j = 0; j < 3; j++) {
      float cy = by + (float)(j - 1) * s;
      float fy0 = floorf(cy);
      yw1[j] = cy - fy0; yw0[j] = 1.f - yw1[j];
      int y0 = min(max((int)fy0, -2), 66);
      int par = y0 & 1;
      int yp = (y0 + 2 - par) >> 1;
      rb[j] = v8 + par * VSZ_B + lmoff + yp * (VROW * 16);
    }
#pragma unroll 1
    for (int jx = 0; jx < 3; jx++) {
      float cx = bx + (float)(jx - 1) * s;
      float fx0 = floorf(cx);
      float wx1 = cx - fx0, wx0 = 1.f - wx1;
      int xoff = (min(max((int)fx0, -2), 66) + 2) * 16;
      const unsigned short* lg3 = lgp + jx * 3;
#pragma unroll
      for (int jy = 0; jy < 3; jy++) {
        float wgt = bf2f(lg3[jy]);         // pre-transformed: exp(logit)
        wsum += wgt;
        const unsigned char* vb = rb[jy] + xoff;
        uint4 qa = *(const uint4*)vb;        // x0:   [slot0 8ch][slot1 8ch]
        uint4 qb = *(const uint4*)(vb + 16); // x0+1

        float w00 = wgt * wx0 * yw0[jy], w01 = wgt * wx0 * yw1[jy];
        float w10 = wgt * wx1 * yw0[jy], w11 = wgt * wx1 * yw1[jy];
        f32x2 W00 = (f32x2){w00, w00}, W01 = (f32x2){w01, w01};
        f32x2 W10 = (f32x2){w10, w10}, W11 = (f32x2){w11, w11};

        accv[0] += W00 * cvt8<false>(qa.x) + W01 * cvt8<false>(qa.z)
                 + W10 * cvt8<false>(qb.x) + W11 * cvt8<false>(qb.z);
        accv[1] += W00 * cvt8<true>(qa.x)  + W01 * cvt8<true>(qa.z)
                 + W10 * cvt8<true>(qb.x)  + W11 * cvt8<true>(qb.z);
        accv[2] += W00 * cvt8<false>(qa.y) + W01 * cvt8<false>(qa.w)
                 + W10 * cvt8<false>(qb.y) + W11 * cvt8<false>(qb.w);
        accv[3] += W00 * cvt8<true>(qa.y)  + W01 * cvt8<true>(qa.w)
                 + W10 * cvt8<true>(qb.y)  + W11 * cvt8<true>(qb.w);
      }
    }
  }
#pragma unroll
  for (int mask = 1; mask < 16; mask <<= 1) {
    wsum += __shfl_xor(wsum, mask);
#pragma unroll
    for (int d = 0; d < 4; d++) {
      accv[d].x += __shfl_xor(accv[d].x, mask);
      accv[d].y += __shfl_xor(accv[d].y, mask);
    }
  }
  if (yl < 8) {
    float inv = __builtin_amdgcn_rcpf(wsum);
    float r = 0.f;
#pragma unroll
    for (int d = 0; d < 8; d++) {
      float v = (d & 1) ? accv[d >> 1].y : accv[d >> 1].x;
      r = (d == yl) ? v : r;
    }
    featL[pl][m * 8 + yl] = r * inv;
  }
  __syncthreads();

  // output conv stage 1: hop = lrelu(W1·feat + b1)
  if (tid < 128) {
    int ql = tid >> 6, co = tid & 63;
    float a = bias1[co];
    const uint4* wr = (const uint4*)(o1b + co * 64);
#pragma unroll
    for (int c8 = 0; c8 < 8; c8++) {
      uint4 wv = wr[c8];
      int ci = c8 * 8;
      a += bf_lo(wv.x) * featL[ql][ci]     + bf_hi(wv.x) * featL[ql][ci + 1]
         + bf_lo(wv.y) * featL[ql][ci + 2] + bf_hi(wv.y) * featL[ql][ci + 3]
         + bf_lo(wv.z) * featL[ql][ci + 4] + bf_hi(wv.z) * featL[ql][ci + 5]
         + bf_lo(wv.w) * featL[ql][ci + 6] + bf_hi(wv.w) * featL[ql][ci + 7];
    }
    hopL[ql][co] = lrelu_f(a);
  }
  __syncthreads();

  // output conv stage 2 + residual
  if (tid < 128) {
    int ql = tid >> 6, co = tid & 63;
    int p2 = blockIdx.x * 2 + ql;
    float a = bias2[co];
    const uint4* wr = (const uint4*)(o2b + co * 64);
#pragma unroll
    for (int c8 = 0; c8 < 8; c8++) {
      uint4 wv = wr[c8];
      int ci = c8 * 8;
      a += bf_lo(wv.x) * hopL[ql][ci]     + bf_hi(wv.x) * hopL[ql][ci + 1]
         + bf_lo(wv.y) * hopL[ql][ci + 2] + bf_hi(wv.y) * hopL[ql][ci + 3]
         + bf_lo(wv.z) * hopL[ql][ci + 4] + bf_hi(wv.z) * hopL[ql][ci + 5]
         + bf_lo(wv.w) * hopL[ql][ci + 6] + bf_hi(wv.w) * hopL[ql][ci + 7];
    }
    out[(size_t)co * HWN + p2] = a + x[(size_t)co * HWN + p2];
  }
}

extern "C" void kernel_launch(void* const* d_in, const int* in_sizes, int n_in,
                              void* d_out, int out_size, void* d_ws, size_t ws_size,
                              hipStream_t stream) {
  const float* x     = (const float*)d_in[0];
  const float* flow1 = (const float*)d_in[1];
  const float* flow2 = (const float*)d_in[2];
  const float* aw_w1 = (const float*)d_in[5];
  const float* aw_b1 = (const float*)d_in[6];
  const float* aw_w2 = (const float*)d_in[7];
  const float* aw_b2 = (const float*)d_in[8];
  const float* aw_w3 = (const float*)d_in[9];
  const float* aw_b3 = (const float*)d_in[10];
  const float* aw_w4 = (const float*)d_in[11];
  const float* aw_b4 = (const float*)d_in[12];
  const float* so_w1 = (const float*)d_in[13];
  const float* so_b1 = (const float*)d_in[14];
  const float* so_w2 = (const float*)d_in[15];
  const float* so_b2 = (const float*)d_in[16];
  const float* so_w3 = (const float*)d_in[17];
  const float* so_b3 = (const float*)d_in[18];
  const float* so_w4 = (const float*)d_in[19];
  const float* so_b4 = (const float*)d_in[20];
  const float* po_w1 = (const float*)d_in[21];
  const float* po_b1 = (const float*)d_in[22];
  const float* po_w2 = (const float*)d_in[23];
  const float* po_b2 = (const float*)d_in[24];
  const float* po_w3 = (const float*)d_in[25];
  const float* po_b3 = (const float*)d_in[26];
  const float* po_w4 = (const float*)d_in[27];
  const float* po_b4 = (const float*)d_in[28];
  const float* vp_w  = (const float*)d_in[29];
  const float* vp_b  = (const float*)d_in[30];
  const float* op_w1 = (const float*)d_in[31];
  const float* op_b1 = (const float*)d_in[32];
  const float* op_w2 = (const float*)d_in[33];
  const float* op_b2 = (const float*)d_in[34];

  char* base = (char*)d_ws;
  size_t off = 0;
  auto alloc = [&](size_t bytes) { void* pp = base + off; off = (off + bytes + 255) & ~(size_t)255; return pp; };

  float* fcn2  = (float*)alloc(2 * HWN * 4);
  unsigned short* xb    = (unsigned short*)alloc(192 * HWN * 2);
  unsigned short* vsb   = (unsigned short*)alloc(192 * HWN * 2);
  unsigned short* extra = (unsigned short*)alloc(224 * HWN * 2);
  unsigned short* h1    = (unsigned short*)alloc(192 * HWN * 2);
  unsigned short* h2    = (unsigned short*)alloc(192 * HWN * 2);
  unsigned short* h3    = (unsigned short*)alloc(192 * HWN * 2);
  unsigned short* to    = (unsigned short*)alloc((size_t)3456 * HWN * 2);
  unsigned char* v8     = (unsigned char*)alloc((size_t)VSZ_B * 2);
  unsigned short* Wtail = (unsigned short*)alloc(3456 * 64 * 2);
  float* btail = (float*)alloc(3456 * 4);
  float* b1c   = (float*)alloc(192 * 4);
  float* b2c   = (float*)alloc(192 * 4);
  float* b3c   = (float*)alloc(192 * 4);
  unsigned short* o1b = (unsigned short*)alloc(64 * 64 * 2);
  unsigned short* o2b = (unsigned short*)alloc(64 * 64 * 2);
  unsigned short* W1  = (unsigned short*)alloc(192 * 224 * 2);
  unsigned short* W2g = (unsigned short*)alloc(3 * 64 * 576 * 2);
  unsigned short* W3g = (unsigned short*)alloc(3 * 64 * 576 * 2);
  unsigned short* vpb = (unsigned short*)alloc(192 * 192 * 2);

  k_pre<<<2302, 256, 0, stream>>>(
      x, flow1, flow2,
      so_w4, po_w4, aw_w4, so_b4, po_b4, aw_b4,
      so_b1, po_b1, aw_b1, so_b2, po_b2, aw_b2, so_b3, po_b3, aw_b3,
      so_w1, po_w1, aw_w1, so_w2, po_w2, aw_w2, so_w3, po_w3, aw_w3,
      op_w1, op_w2, vp_w,
      Wtail, btail, b1c, b2c, b3c, o1b, o2b, W1, W2g, W3g, vpb, xb, fcn2, v8);

  k_extra<<<1024, 256, 0, stream>>>(xb, flow1, fcn2, extra);

  // z=0: value proj xb->vsb; z=1: trunk head extra->h1
  k_gemm2<<<dim3(128, 6, 2), 128, 0, stream>>>(xb, vpb, vp_b, vsb, extra, W1, b1c, h1);

  // z<3: grouped conv h1->h2; z==3: vsb -> fp8 repack
  k_conv3g<<<dim3(128, 4, 4), 128, 0, stream>>>(h1, W2g, b2c, h2, vsb, v8);
  // second 3x3 conv h2->h3 (no repack plane)
  k_conv3g<<<dim3(128, 4, 3), 128, 0, stream>>>(h2, W3g, b3c, h3, vsb, v8);

  // tail GEMM -> to
  k_tail<<<dim3(64, 108), 256, 0, stream>>>(h3, Wtail, btail, to);

  // fused sampling + softmax + output convs + residual
  k_msdout<<<2048, 256, 0, stream>>>(v8, to, flow1, fcn2, o1b, op_b1, o2b, op_b2, x, (float*)d_out);
}

// Round 20
// 222.011 us; speedup vs baseline: 1.1572x; 1.0266x over previous
//
#include <hip/hip_runtime.h>
#include <hip/hip_bf16.h>
#include <math.h>

// n=1, t=3(=L), c=64, h=w=64, M=8, D=8, P=12, KK=9
#define HWN 4096
// fp8 dual-copy value layout: [24 lm][36 yp][72 x][2 slot][8 ch] BYTES
#define VROW 72
#define VYP 36
#define VSZ_B (24 * VYP * VROW * 16)   // 995328 bytes per copy

typedef __attribute__((ext_vector_type(8))) short short8;
typedef __attribute__((ext_vector_type(4))) float f32x4;
typedef __attribute__((ext_vector_type(2))) float f32x2;

__device__ __forceinline__ float lrelu_f(float v) { return v >= 0.f ? v : 0.1f * v; }

__device__ __forceinline__ unsigned short f2bf(float f) {
  union { float f; unsigned u; } v; v.f = f;
  unsigned r = v.u + 0x7fff + ((v.u >> 16) & 1);   // round-to-nearest-even
  return (unsigned short)(r >> 16);
}
__device__ __forceinline__ float bf2f(unsigned short u) {
  union { unsigned u; float f; } v; v.u = ((unsigned)u) << 16; return v.f;
}
__device__ __forceinline__ float bf_lo(unsigned u) {
  union { unsigned u; float f; } v; v.u = u << 16; return v.f;
}
__device__ __forceinline__ float bf_hi(unsigned u) {
  union { unsigned u; float f; } v; v.u = u & 0xffff0000u; return v.f;
}
// word-select must be an immediate constant -> template parameter
template <bool HI>
__device__ __forceinline__ f32x2 cvt8(unsigned u) {
  return __builtin_amdgcn_cvt_pk_f32_fp8((int)u, HI);
}

__device__ __forceinline__ float bilin_zero(const float* __restrict__ img, float ix, float iy) {
  float fx0 = floorf(ix), fy0 = floorf(iy);
  int x0 = (int)fx0, y0 = (int)fy0;
  float wx1 = ix - fx0, wy1 = iy - fy0;
  float wx0 = 1.f - wx1, wy0 = 1.f - wy1;
  float acc = 0.f;
  if ((unsigned)y0 < 64u) {
    if ((unsigned)x0 < 64u)       acc += wx0 * wy0 * img[y0 * 64 + x0];
    if ((unsigned)(x0 + 1) < 64u) acc += wx1 * wy0 * img[y0 * 64 + x0 + 1];
  }
  if ((unsigned)(y0 + 1) < 64u) {
    if ((unsigned)x0 < 64u)       acc += wx0 * wy1 * img[(y0 + 1) * 64 + x0];
    if ((unsigned)(x0 + 1) < 64u) acc += wx1 * wy1 * img[(y0 + 1) * 64 + x0 + 1];
  }
  return acc;
}

// k_pre segments (by blockIdx.x):
// [0,864) Wtail | [864,912) biases+op | [912,1080) W1 | [1080,1464) W2g/W3g
// [1464,1608) vpb | [1608,1800) x transpose | [1800,1816) flow_cn2
// [1816,2302) zero v8 (fp8, 2*VSZ_B bytes)
__global__ void k_pre(
    const float* __restrict__ x, const float* __restrict__ flow1, const float* __restrict__ flow2,
    const float* so_w4, const float* po_w4, const float* aw_w4,
    const float* so_b4, const float* po_b4, const float* aw_b4,
    const float* so_b1, const float* po_b1, const float* aw_b1,
    const float* so_b2, const float* po_b2, const float* aw_b2,
    const float* so_b3, const float* po_b3, const float* aw_b3,
    const float* so_w1, const float* po_w1, const float* aw_w1,
    const float* so_w2, const float* po_w2, const float* aw_w2,
    const float* so_w3, const float* po_w3, const float* aw_w3,
    const float* op_w1, const float* op_w2, const float* vp_w,
    unsigned short* Wtail, float* btail, float* b1c, float* b2c, float* b3c,
    unsigned short* o1b, unsigned short* o2b, unsigned short* W1,
    unsigned short* W2g, unsigned short* W3g, unsigned short* vpb,
    unsigned short* xb, float* fcn2, unsigned char* v8) {
  __shared__ unsigned short tile[64 * 65];
  __shared__ unsigned short wrow[576];
  int gx = blockIdx.x;
  int tid = threadIdx.x;
  if (gx < 864) {  // Wtail [3456][64]
    int t = gx * 256 + tid;
    int row = t >> 6, k = t & 63;
    float v = row < 576 ? so_w4[row * 64 + k]
            : row < 864 ? po_w4[(row - 576) * 64 + k]
                        : aw_w4[(row - 864) * 64 + k];
    Wtail[t] = f2bf(v);
  } else if (gx < 912) {
    int t = (gx - 864) * 256 + tid;
    if (t < 3456) {
      btail[t] = t < 576 ? so_b4[t] : t < 864 ? po_b4[t - 576] : aw_b4[t - 864];
    } else if (t < 3648) {
      int i = t - 3456; b1c[i] = i < 64 ? so_b1[i] : i < 128 ? po_b1[i - 64] : aw_b1[i - 128];
    } else if (t < 3840) {
      int i = t - 3648; b2c[i] = i < 64 ? so_b2[i] : i < 128 ? po_b2[i - 64] : aw_b2[i - 128];
    } else if (t < 4032) {
      int i = t - 3840; b3c[i] = i < 64 ? so_b3[i] : i < 128 ? po_b3[i - 64] : aw_b3[i - 128];
    } else if (t < 8128) {
      o1b[t - 4032] = f2bf(op_w1[t - 4032]);
    } else if (t < 12224) {
      o2b[t - 8128] = f2bf(op_w2[t - 8128]);
    }
  } else if (gx < 1080) {  // W1 [192][224] zero-padded K
    int t = (gx - 912) * 256 + tid;
    if (t < 192 * 224) {
      int row = t / 224, k = t % 224;
      int tr = row >> 6, lco = row & 63;
      const float* s = tr == 0 ? so_w1 : tr == 1 ? po_w1 : aw_w1;
      W1[t] = (k < 196) ? f2bf(s[lco * 196 + k]) : (unsigned short)0;
    }
  } else if (gx < 1464) {  // W2g/W3g LDS transpose
    int b = gx - 1080;
    int which = b >= 192;
    b &= 191;
    int tr = b >> 6, co = b & 63;
    const float* s;
    if (!which) s = tr == 0 ? so_w2 : tr == 1 ? po_w2 : aw_w2;
    else        s = tr == 0 ? so_w3 : tr == 1 ? po_w3 : aw_w3;
    unsigned short* d = which ? W3g : W2g;
#pragma unroll
    for (int j = tid; j < 576; j += 256) wrow[j] = f2bf(s[co * 576 + j]);
    __syncthreads();
#pragma unroll
    for (int j = tid; j < 576; j += 256)
      d[((size_t)tr * 64 + co) * 576 + j] = wrow[(j & 63) * 9 + (j >> 6)];
  } else if (gx < 1608) {  // vpb [192][192]
    int t = (gx - 1464) * 256 + tid;
    if (t < 192 * 192) vpb[t] = f2bf(vp_w[t]);
  } else if (gx < 1800) {  // x transpose -> xb [p][192]
    int b = gx - 1608;
    int ptile = b & 63, cg = b >> 6;  // 64 x 3
    int px = tid & 63, ch0 = (tid >> 6) * 16;
#pragma unroll
    for (int i = 0; i < 16; i++) {
      float v = x[(size_t)(cg * 64 + ch0 + i) * HWN + ptile * 64 + px];
      tile[(ch0 + i) * 65 + px] = f2bf(v);
    }
    __syncthreads();
    int c = tid & 63, pl0 = (tid >> 6) * 16;
#pragma unroll
    for (int i = 0; i < 16; i++)
      xb[(size_t)(ptile * 64 + pl0 + i) * 192 + cg * 64 + c] = tile[c * 65 + pl0 + i];
  } else if (gx < 1816) {  // flow_cn2
    int p = (gx - 1800) * 256 + tid;
    int px = p & 63, py = p >> 6;
    float fx = flow1[p], fy = flow1[HWN + p];
    float ix = (float)px + fx, iy = (float)py + fy;
    fcn2[p] = fx + bilin_zero(flow2, ix, iy);
    fcn2[HWN + p] = fy + bilin_zero(flow2 + HWN, ix, iy);
  } else {  // zero fp8 tables: 2*VSZ_B/16 = 124416 uint4
    int i = (gx - 1816) * 256 + tid;
    if (i < 2 * VSZ_B / 16) ((uint4*)v8)[i] = make_uint4(0, 0, 0, 0);
  }
}

// k_extra: wave per pixel, lane = channel. All accesses coalesced.
__global__ void k_extra(const unsigned short* __restrict__ xb, const float* __restrict__ flow1,
                        const float* __restrict__ fcn2, unsigned short* __restrict__ extra) {
  int w = threadIdx.x >> 6, c = threadIdx.x & 63;
  int p = blockIdx.x * 4 + w;
  int px = p & 63, py = p >> 6;
  float fx1 = flow1[p], fy1 = flow1[HWN + p];
  float fx2 = fcn2[p],  fy2 = fcn2[HWN + p];
  extra[(size_t)p * 224 + c] = xb[(size_t)p * 192 + c];
#pragma unroll
  for (int lev = 0; lev < 2; lev++) {
    float ix = (float)px + (lev ? fx2 : fx1);
    float iy = (float)py + (lev ? fy2 : fy1);
    float fx0 = floorf(ix), fy0 = floorf(iy);
    int x0 = (int)fx0, y0 = (int)fy0;
    float wx1 = ix - fx0, wy1 = iy - fy0;
    float wx0 = 1.f - wx1, wy0 = 1.f - wy1;
    int coff = (lev + 1) * 64;
    float acc = 0.f;
    if ((unsigned)y0 < 64u) {
      if ((unsigned)x0 < 64u)       acc += wx0 * wy0 * bf2f(xb[(size_t)(y0 * 64 + x0) * 192 + coff + c]);
      if ((unsigned)(x0 + 1) < 64u) acc += wx1 * wy0 * bf2f(xb[(size_t)(y0 * 64 + x0 + 1) * 192 + coff + c]);
    }
    if ((unsigned)(y0 + 1) < 64u) {
      if ((unsigned)x0 < 64u)       acc += wx0 * wy1 * bf2f(xb[(size_t)((y0 + 1) * 64 + x0) * 192 + coff + c]);
      if ((unsigned)(x0 + 1) < 64u) acc += wx1 * wy1 * bf2f(xb[(size_t)((y0 + 1) * 64 + x0 + 1) * 192 + coff + c]);
    }
    extra[(size_t)p * 224 + coff + c] = f2bf(acc);
  }
  if (c < 2) {
    extra[(size_t)p * 224 + 192 + c] = f2bf(flow1[c * HWN + p]);
    extra[(size_t)p * 224 + 194 + c] = f2bf(fcn2[c * HWN + p]);
  }
  if (c < 28) extra[(size_t)p * 224 + 196 + c] = 0;
}

// Two GEMMs in one dispatch (blockIdx.z): z=0 value-proj (K=192), z=1 trunk head (K=224, lrelu).
__global__ __launch_bounds__(128) void k_gemm2(
    const unsigned short* __restrict__ A0, const unsigned short* __restrict__ Wm0,
    const float* __restrict__ bias0, unsigned short* __restrict__ out0,
    const unsigned short* __restrict__ A1, const unsigned short* __restrict__ Wm1,
    const float* __restrict__ bias1, unsigned short* __restrict__ out1) {
  int z = blockIdx.z;
  const unsigned short* A = z ? A1 : A0;
  const unsigned short* Wm = z ? Wm1 : Wm0;
  const float* bias = z ? bias1 : bias0;
  unsigned short* out = z ? out1 : out0;
  int K = z ? 224 : 192;

  int wv = threadIdx.x >> 6;
  int l = threadIdx.x & 63;
  int lm = l & 15, lq = l >> 4;
  int p0 = blockIdx.x * 32 + wv * 16;
  int co0 = blockIdx.y * 32;

  f32x4 acc[2];
#pragma unroll
  for (int nt = 0; nt < 2; nt++) {
    float bv = bias[co0 + nt * 16 + lm];
    acc[nt] = (f32x4){bv, bv, bv, bv};
  }
  const unsigned short* ap = A + (size_t)(p0 + lm) * K + lq * 8;
  const unsigned short* wp = Wm + (size_t)(co0 + lm) * K + lq * 8;
  for (int k0 = 0; k0 < K; k0 += 32) {
    short8 af = *(const short8*)(ap + k0);
#pragma unroll
    for (int nt = 0; nt < 2; nt++) {
      short8 bf = *(const short8*)(wp + (size_t)nt * 16 * K + k0);
      acc[nt] = __builtin_amdgcn_mfma_f32_16x16x32_bf16(af, bf, acc[nt], 0, 0, 0);
    }
  }
#pragma unroll
  for (int nt = 0; nt < 2; nt++) {
    int co = co0 + nt * 16 + lm;
#pragma unroll
    for (int r = 0; r < 4; r++) {
      int p = p0 + lq * 4 + r;
      float v = acc[nt][r];
      if (z) v = lrelu_f(v);
      out[(size_t)p * 192 + co] = f2bf(v);
    }
  }
}

// Grouped direct 3x3 conv (pad 1) as MFMA GEMM over shifted rows of h [p][192].
__global__ __launch_bounds__(128) void k_conv3g(const unsigned short* __restrict__ h,
                                                const unsigned short* __restrict__ Wm,
                                                const float* __restrict__ bias,
                                                unsigned short* __restrict__ out) {
  int wv = threadIdx.x >> 6;
  int l = threadIdx.x & 63;
  int lm = l & 15, lq = l >> 4;
  int p0 = blockIdx.x * 32 + wv * 16;
  int co0 = blockIdx.y * 16;
  int t = blockIdx.z;
  int p = p0 + lm;
  int px = p & 63, py = p >> 6;

  float bv = bias[t * 64 + co0 + lm];
  f32x4 acc = (f32x4){bv, bv, bv, bv};
  const unsigned short* wp = Wm + ((size_t)t * 64 + co0 + lm) * 576 + lq * 8;
#pragma unroll
  for (int kidx = 0; kidx < 9; kidx++) {
    int ky = kidx / 3, kx = kidx % 3;
    int pp = p + (ky - 1) * 64 + (kx - 1);
    bool valid = ((unsigned)(px + kx - 1) < 64u) && ((unsigned)(py + ky - 1) < 64u);
    const unsigned short* apb = h + (size_t)pp * 192 + t * 64 + lq * 8;
#pragma unroll
    for (int c2 = 0; c2 < 2; c2++) {
      short8 af = {};
      if (valid) af = *(const short8*)(apb + c2 * 32);
      short8 bf = *(const short8*)(wp + kidx * 64 + c2 * 32);
      acc = __builtin_amdgcn_mfma_f32_16x16x32_bf16(af, bf, acc, 0, 0, 0);
    }
  }
#pragma unroll
  for (int r = 0; r < 4; r++) {
    int po_ = p0 + lq * 4 + r;
    out[(size_t)po_ * 192 + t * 64 + co0 + lm] = f2bf(lrelu_f(acc[r]));
  }
}

// k_tail: y<108: trunk 1x1 tails (+exp/3*sigmoid epilogue); y in [108,114): fp8 repack.
__global__ __launch_bounds__(256) void k_tail(const unsigned short* __restrict__ A,
                                              const unsigned short* __restrict__ Wm,
                                              const float* __restrict__ bias,
                                              unsigned short* __restrict__ out,
                                              const unsigned short* __restrict__ vsb,
                                              unsigned char* __restrict__ v8) {
  if (blockIdx.y >= 108) {  // repack vsb [p][192] bf16 -> fp8 dual copies
    int i = ((blockIdx.y - 108) * 64 + blockIdx.x) * 256 + threadIdx.x;  // < 98304
    int lm = i % 24, p = i / 24;
    uint4 vv = ((const uint4*)vsb)[p * 24 + lm];
    int lo = 0, hi = 0;
    lo = __builtin_amdgcn_cvt_pk_fp8_f32(bf_lo(vv.x), bf_hi(vv.x), lo, false);
    lo = __builtin_amdgcn_cvt_pk_fp8_f32(bf_lo(vv.y), bf_hi(vv.y), lo, true);
    hi = __builtin_amdgcn_cvt_pk_fp8_f32(bf_lo(vv.z), bf_hi(vv.z), hi, false);
    hi = __builtin_amdgcn_cvt_pk_fp8_f32(bf_lo(vv.w), bf_hi(vv.w), hi, true);
    uint2 pk; pk.x = (unsigned)lo; pk.y = (unsigned)hi;
    int y = p >> 6, xx = p & 63;
    int ypA = (y >> 1) + 1, slotA = y & 1;
    int ypB = (y + 1) >> 1, slotB = (y & 1) ^ 1;
    *(uint2*)(v8 + (((lm * VYP + ypA) * VROW + xx + 2) * 16 + slotA * 8)) = pk;
    *(uint2*)(v8 + VSZ_B + (((lm * VYP + ypB) * VROW + xx + 2) * 16 + slotB * 8)) = pk;
    return;
  }
  int wv = threadIdx.x >> 6;
  int l = threadIdx.x & 63;
  int lm = l & 15, lq = l >> 4;
  int p0 = blockIdx.x * 64 + wv * 16;
  int co0 = blockIdx.y * 32;
  int t = (co0 < 576) ? 0 : (co0 < 864 ? 1 : 2);

  f32x4 acc[2];
#pragma unroll
  for (int nt = 0; nt < 2; nt++) {
    float bv = bias[co0 + nt * 16 + lm];
    acc[nt] = (f32x4){bv, bv, bv, bv};
  }
  const unsigned short* ap = A + (size_t)(p0 + lm) * 192 + t * 64 + lq * 8;
  const unsigned short* wp = Wm + (size_t)(co0 + lm) * 64 + lq * 8;
#pragma unroll
  for (int k0 = 0; k0 < 64; k0 += 32) {
    short8 af = *(const short8*)(ap + k0);
#pragma unroll
    for (int nt = 0; nt < 2; nt++) {
      short8 bf = *(const short8*)(wp + (size_t)nt * 16 * 64 + k0);
      acc[nt] = __builtin_amdgcn_mfma_f32_16x16x32_bf16(af, bf, acc[nt], 0, 0, 0);
    }
  }
#pragma unroll
  for (int nt = 0; nt < 2; nt++) {
    int co = co0 + nt * 16 + lm;
#pragma unroll
    for (int r = 0; r < 4; r++) {
      int p = p0 + lq * 4 + r;
      float v = acc[nt][r];
      if (t == 2) v = __expf(v);                                            // aw -> exp(logit)
      else if (t == 1) v = 3.f * __builtin_amdgcn_rcpf(1.f + __expf(-v));   // po -> 3*sigmoid
      out[(size_t)p * 3456 + co] = f2bf(v);
    }
  }
}

// Fused softmax + deformable sampling + output convs + residual.
// Block = 256 thr = 2 pixels x 8 heads x 16 lanes.
__global__ __launch_bounds__(256, 4) void k_msdout(
    const unsigned char* __restrict__ v8,
    const unsigned short* __restrict__ to,
    const float* __restrict__ flow1, const float* __restrict__ fcn2,
    const unsigned short* __restrict__ o1b, const float* __restrict__ bias1,
    const unsigned short* __restrict__ o2b, const float* __restrict__ bias2,
    const float* __restrict__ x, float* __restrict__ out) {
  __shared__ float featL[2][64];
  __shared__ float hopL[2][64];
  int tid = threadIdx.x;
  int yl = tid & 15;
  int m = (tid >> 4) & 7;
  int pl = tid >> 7;
  int p = blockIdx.x * 2 + pl;
  int px = p & 63, py = p >> 6;

  float fx1 = flow1[p], fy1 = flow1[HWN + p];
  float fx2 = fcn2[p],  fy2 = fcn2[HWN + p];

  const unsigned short* row = to + (size_t)p * 3456;

  f32x2 accv[4];
#pragma unroll
  for (int d = 0; d < 4; d++) accv[d] = (f32x2){0.f, 0.f};
  float wsum = 0.f;

#pragma unroll 1
  for (int pair = yl; pair < 36; pair += 16) {
    int lv = pair / 12, pt = pair % 12;
    float fx = (lv == 1) ? fx1 : ((lv == 2) ? fx2 : 0.f);
    float fy = (lv == 1) ? fy1 : ((lv == 2) ? fy2 : 0.f);
    int ch = (m * 3 + lv) * 12 + pt;
    unsigned ow = *(const unsigned*)(row + ch * 2);
    float ox = bf_lo(ow);
    float oy = bf_hi(ow);
    float s = bf2f(row[576 + ch]);         // pre-transformed: 3*sigmoid(po)
    float bx = (float)px + ox + fx;
    float by = (float)py + oy + fy;
    int lmoff = (lv * 8 + m) * (VYP * VROW * 16);
    const unsigned short* lgp = row + 864 + m * 324 + lv * 108 + pt * 9;

    // y-side precompute (constant indices after unroll)
    const unsigned char* rb[3];
    float yw0[3], yw1[3];
#pragma unroll
    for (int j = 0; j < 3; j++) {
      float cy = by + (float)(j - 1) * s;
      float fy0 = floorf(cy);
      yw1[j] = cy - fy0; yw0[j] = 1.f - yw1[j];
      int y0 = min(max((int)fy0, -2), 66);
      int par = y0 & 1;
      int yp = (y0 + 2 - par) >> 1;
      rb[j] = v8 + par * VSZ_B + lmoff + yp * (VROW * 16);
    }
#pragma unroll 1
    for (int jx = 0; jx < 3; jx++) {
      float cx = bx + (float)(jx - 1) * s;
      float fx0 = floorf(cx);
      float wx1 = cx - fx0, wx0 = 1.f - wx1;
      int xoff = (min(max((int)fx0, -2), 66) + 2) * 16;
      const unsigned short* lg3 = lgp + jx * 3;
#pragma unroll
      for (int jy = 0; jy < 3; jy++) {
        float wgt = bf2f(lg3[jy]);         // pre-transformed: exp(logit)
        wsum += wgt;
        const unsigned char* vb = rb[jy] + xoff;
        uint4 qa = *(const uint4*)vb;        // x0:   [slot0 8ch][slot1 8ch]
        uint4 qb = *(const uint4*)(vb + 16); // x0+1

        float w00 = wgt * wx0 * yw0[jy], w01 = wgt * wx0 * yw1[jy];
        float w10 = wgt * wx1 * yw0[jy], w11 = wgt * wx1 * yw1[jy];
        f32x2 W00 = (f32x2){w00, w00}, W01 = (f32x2){w01, w01};
        f32x2 W10 = (f32x2){w10, w10}, W11 = (f32x2){w11, w11};

        accv[0] += W00 * cvt8<false>(qa.x) + W01 * cvt8<false>(qa.z)
                 + W10 * cvt8<false>(qb.x) + W11 * cvt8<false>(qb.z);
        accv[1] += W00 * cvt8<true>(qa.x)  + W01 * cvt8<true>(qa.z)
                 + W10 * cvt8<true>(qb.x)  + W11 * cvt8<true>(qb.z);
        accv[2] += W00 * cvt8<false>(qa.y) + W01 * cvt8<false>(qa.w)
                 + W10 * cvt8<false>(qb.y) + W11 * cvt8<false>(qb.w);
        accv[3] += W00 * cvt8<true>(qa.y)  + W01 * cvt8<true>(qa.w)
                 + W10 * cvt8<true>(qb.y)  + W11 * cvt8<true>(qb.w);
      }
    }
  }
#pragma unroll
  for (int mask = 1; mask < 16; mask <<= 1) {
    wsum += __shfl_xor(wsum, mask);
#pragma unroll
    for (int d = 0; d < 4; d++) {
      accv[d].x += __shfl_xor(accv[d].x, mask);
      accv[d].y += __shfl_xor(accv[d].y, mask);
    }
  }
  if (yl < 8) {
    float inv = __builtin_amdgcn_rcpf(wsum);
    float r = 0.f;
#pragma unroll
    for (int d = 0; d < 8; d++) {
      float v = (d & 1) ? accv[d >> 1].y : accv[d >> 1].x;
      r = (d == yl) ? v : r;
    }
    featL[pl][m * 8 + yl] = r * inv;
  }
  __syncthreads();

  // output conv stage 1: hop = lrelu(W1·feat + b1)
  if (tid < 128) {
    int ql = tid >> 6, co = tid & 63;
    float a = bias1[co];
    const uint4* wr = (const uint4*)(o1b + co * 64);
#pragma unroll
    for (int c8 = 0; c8 < 8; c8++) {
      uint4 wv = wr[c8];
      int ci = c8 * 8;
      a += bf_lo(wv.x) * featL[ql][ci]     + bf_hi(wv.x) * featL[ql][ci + 1]
         + bf_lo(wv.y) * featL[ql][ci + 2] + bf_hi(wv.y) * featL[ql][ci + 3]
         + bf_lo(wv.z) * featL[ql][ci + 4] + bf_hi(wv.z) * featL[ql][ci + 5]
         + bf_lo(wv.w) * featL[ql][ci + 6] + bf_hi(wv.w) * featL[ql][ci + 7];
    }
    hopL[ql][co] = lrelu_f(a);
  }
  __syncthreads();

  // output conv stage 2 + residual
  if (tid < 128) {
    int ql = tid >> 6, co = tid & 63;
    int p2 = blockIdx.x * 2 + ql;
    float a = bias2[co];
    const uint4* wr = (const uint4*)(o2b + co * 64);
#pragma unroll
    for (int c8 = 0; c8 < 8; c8++) {
      uint4 wv = wr[c8];
      int ci = c8 * 8;
      a += bf_lo(wv.x) * hopL[ql][ci]     + bf_hi(wv.x) * hopL[ql][ci + 1]
         + bf_lo(wv.y) * hopL[ql][ci + 2] + bf_hi(wv.y) * hopL[ql][ci + 3]
         + bf_lo(wv.z) * hopL[ql][ci + 4] + bf_hi(wv.z) * hopL[ql][ci + 5]
         + bf_lo(wv.w) * hopL[ql][ci + 6] + bf_hi(wv.w) * hopL[ql][ci + 7];
    }
    out[(size_t)co * HWN + p2] = a + x[(size_t)co * HWN + p2];
  }
}

extern "C" void kernel_launch(void* const* d_in, const int* in_sizes, int n_in,
                              void* d_out, int out_size, void* d_ws, size_t ws_size,
                              hipStream_t stream) {
  const float* x     = (const float*)d_in[0];
  const float* flow1 = (const float*)d_in[1];
  const float* flow2 = (const float*)d_in[2];
  const float* aw_w1 = (const float*)d_in[5];
  const float* aw_b1 = (const float*)d_in[6];
  const float* aw_w2 = (const float*)d_in[7];
  const float* aw_b2 = (const float*)d_in[8];
  const float* aw_w3 = (const float*)d_in[9];
  const float* aw_b3 = (const float*)d_in[10];
  const float* aw_w4 = (const float*)d_in[11];
  const float* aw_b4 = (const float*)d_in[12];
  const float* so_w1 = (const float*)d_in[13];
  const float* so_b1 = (const float*)d_in[14];
  const float* so_w2 = (const float*)d_in[15];
  const float* so_b2 = (const float*)d_in[16];
  const float* so_w3 = (const float*)d_in[17];
  const float* so_b3 = (const float*)d_in[18];
  const float* so_w4 = (const float*)d_in[19];
  const float* so_b4 = (const float*)d_in[20];
  const float* po_w1 = (const float*)d_in[21];
  const float* po_b1 = (const float*)d_in[22];
  const float* po_w2 = (const float*)d_in[23];
  const float* po_b2 = (const float*)d_in[24];
  const float* po_w3 = (const float*)d_in[25];
  const float* po_b3 = (const float*)d_in[26];
  const float* po_w4 = (const float*)d_in[27];
  const float* po_b4 = (const float*)d_in[28];
  const float* vp_w  = (const float*)d_in[29];
  const float* vp_b  = (const float*)d_in[30];
  const float* op_w1 = (const float*)d_in[31];
  const float* op_b1 = (const float*)d_in[32];
  const float* op_w2 = (const float*)d_in[33];
  const float* op_b2 = (const float*)d_in[34];

  char* base = (char*)d_ws;
  size_t off = 0;
  auto alloc = [&](size_t bytes) { void* pp = base + off; off = (off + bytes + 255) & ~(size_t)255; return pp; };

  float* fcn2  = (float*)alloc(2 * HWN * 4);
  unsigned short* xb    = (unsigned short*)alloc(192 * HWN * 2);
  unsigned short* vsb   = (unsigned short*)alloc(192 * HWN * 2);
  unsigned short* extra = (unsigned short*)alloc(224 * HWN * 2);
  unsigned short* h1    = (unsigned short*)alloc(192 * HWN * 2);
  unsigned short* h2    = (unsigned short*)alloc(192 * HWN * 2);
  unsigned short* h3    = (unsigned short*)alloc(192 * HWN * 2);
  unsigned short* to    = (unsigned short*)alloc((size_t)3456 * HWN * 2);
  unsigned char* v8     = (unsigned char*)alloc((size_t)VSZ_B * 2);
  unsigned short* Wtail = (unsigned short*)alloc(3456 * 64 * 2);
  float* btail = (float*)alloc(3456 * 4);
  float* b1c   = (float*)alloc(192 * 4);
  float* b2c   = (float*)alloc(192 * 4);
  float* b3c   = (float*)alloc(192 * 4);
  unsigned short* o1b = (unsigned short*)alloc(64 * 64 * 2);
  unsigned short* o2b = (unsigned short*)alloc(64 * 64 * 2);
  unsigned short* W1  = (unsigned short*)alloc(192 * 224 * 2);
  unsigned short* W2g = (unsigned short*)alloc(3 * 64 * 576 * 2);
  unsigned short* W3g = (unsigned short*)alloc(3 * 64 * 576 * 2);
  unsigned short* vpb = (unsigned short*)alloc(192 * 192 * 2);

  k_pre<<<2302, 256, 0, stream>>>(
      x, flow1, flow2,
      so_w4, po_w4, aw_w4, so_b4, po_b4, aw_b4,
      so_b1, po_b1, aw_b1, so_b2, po_b2, aw_b2, so_b3, po_b3, aw_b3,
      so_w1, po_w1, aw_w1, so_w2, po_w2, aw_w2, so_w3, po_w3, aw_w3,
      op_w1, op_w2, vp_w,
      Wtail, btail, b1c, b2c, b3c, o1b, o2b, W1, W2g, W3g, vpb, xb, fcn2, v8);

  k_extra<<<1024, 256, 0, stream>>>(xb, flow1, fcn2, extra);

  // z=0: value proj xb->vsb; z=1: trunk head extra->h1
  k_gemm2<<<dim3(128, 6, 2), 128, 0, stream>>>(xb, vpb, vp_b, vsb, extra, W1, b1c, h1);

  k_conv3g<<<dim3(128, 4, 3), 128, 0, stream>>>(h1, W2g, b2c, h2);
  k_conv3g<<<dim3(128, 4, 3), 128, 0, stream>>>(h2, W3g, b3c, h3);
  // y<108: tail GEMM; y in [108,114): vsb -> fp8 repack
  k_tail<<<dim3(64, 114), 256, 0, stream>>>(h3, Wtail, btail, to, vsb, v8);

  // fused sampling + softmax + output convs + residual
  k_msdout<<<2048, 256, 0, stream>>>(v8, to, flow1, fcn2, o1b, op_b1, o2b, op_b2, x, (float*)d_out);
}